// Round 8
// baseline (381.812 us; speedup 1.0000x reference)
//
#include <hip/hip_runtime.h>
#include <hip/hip_bf16.h>
#include <stdint.h>

// Problem constants (FC_Caps): B=32, I=1024, O=64, D_out=32, D_in=16
#define B_   32
#define I_   1024
#define O_   64
#define D_   32
#define N_   16
#define OD_  2048   // O_*D_
#define NCH0 64     // iter-0 chunk count (16 i per chunk) — keeps ws at proven 140.25 MiB

// ---------- bf16 helpers (bit-exact RNE pack, shift unpack) ----------
__device__ __forceinline__ uint32_t f2bf1(float f) {
  uint32_t u = __float_as_uint(f);
  return (u + 0x7fffu + ((u >> 16) & 1u)) >> 16;
}
__device__ __forceinline__ uint32_t pack2(float a, float b) {
  return f2bf1(a) | (f2bf1(b) << 16);
}
__device__ __forceinline__ float bflo(uint32_t v) { return __uint_as_float(v << 16); }
__device__ __forceinline__ float bfhi(uint32_t v) { return __uint_as_float(v & 0xffff0000u); }
__device__ __forceinline__ void unpack8(uint4 r, float* u) {
  u[0] = bflo(r.x); u[1] = bfhi(r.x);
  u[2] = bflo(r.y); u[3] = bfhi(r.y);
  u[4] = bflo(r.z); u[5] = bfhi(r.z);
  u[6] = bflo(r.w); u[7] = bfhi(r.w);
}

// ---------- K1v5: fused einsum + iter-0 chunk sums, occupancy-restored ----------
// POST-MORTEM R6: K1v4 = 134 us. XCD co-location WORKED (FETCH 376->66.6 MB)
// but kernel became latency-bound: VALUBusy 23.6%, HBM 19.6%, occupancy 39%
// — grid 1024 = 4 blocks/CU = 4 waves/SIMD can't hide W-load latency.
// Fix (single variable): bb-octet -> bb-QUARTET, grid 2048 = 8 blocks/CU
// = 8 waves/SIMD; __launch_bounds__(256,8) pins VGPR <= 64 (m69: 32 waves/CU
// holds through 64 VGPR). The 8 siblings sharing a W slice stay on ONE XCD
// with consecutive intra-XCD order (R6-validated L2 MSHR merge mechanism).
// LDS pattern / FMA order / store pattern / numerics byte-identical.
__global__ __launch_bounds__(256, 8) void k_einsum_sum(const float* __restrict__ x,
                                                       const float* __restrict__ W,
                                                       uint16_t* __restrict__ uhat,
                                                       uint16_t* __restrict__ part0) {
  const int bx      = blockIdx.x;
  const int xcd     = bx & 7;         // XCD under round-robin dispatch
  const int k       = bx >> 3;        // 0..255: this XCD's dispatch sequence
  const int bbs     = k & 7;          // sibling index — same-XCD adjacent
  const int g       = (xcd << 5) | (k >> 3);  // 0..255 W-slice group
  const int chunk   = g >> 2;         // 0..63
  const int quarter = g & 3;          // 0..3  (512 od each)
  const int t       = threadIdx.x;
  const int od0     = quarter * 512 + t;   // row A; row B = od0 + 256
  const int i0      = chunk * 16;
  const int b0      = bbs * 4;
  __shared__ float xs[16 * 4 * 16];   // [ii][bb][n] = 4 KB
  {                                   // stage 1024 floats: one float4 per thread
    const int bb = t >> 6, rem = t & 63;  // rem = ii*4 + n4
    const int ii = rem >> 2, n4 = rem & 3;
    float4 f = *(const float4*)(x + (size_t)(b0 + bb) * (I_ * N_) +
                                (size_t)(i0 + ii) * N_ + n4 * 4);
    *(float4*)(xs + ii * 64 + bb * 16 + n4 * 4) = f;
  }
  __syncthreads();
  float accA[4], accB[4];
  #pragma unroll
  for (int bb = 0; bb < 4; ++bb) { accA[bb] = 0.f; accB[bb] = 0.f; }
  for (int ii = 0; ii < 16; ++ii) {   // i-loop rolled (keeps I-cache small)
    const int i = i0 + ii;
    float wA[16], wB[16];
    {
      const float4* Wa = (const float4*)(W + (size_t)i * (OD_ * N_) + (size_t)od0 * N_);
      const float4* Wb = (const float4*)(W + (size_t)i * (OD_ * N_) + (size_t)(od0 + 256) * N_);
      #pragma unroll
      for (int qq = 0; qq < 4; ++qq) {
        float4 fa = Wa[qq];
        wA[qq * 4 + 0] = fa.x; wA[qq * 4 + 1] = fa.y;
        wA[qq * 4 + 2] = fa.z; wA[qq * 4 + 3] = fa.w;
        float4 fb = Wb[qq];
        wB[qq * 4 + 0] = fb.x; wB[qq * 4 + 1] = fb.y;
        wB[qq * 4 + 2] = fb.z; wB[qq * 4 + 3] = fb.w;
      }
    }
    #pragma unroll
    for (int bb = 0; bb < 4; ++bb) {
      const float4* xp = (const float4*)(xs + ii * 64 + bb * 16);  // wave-uniform broadcast
      float4 x0 = xp[0], x1 = xp[1], x2 = xp[2], x3 = xp[3];
      float xv[16] = {x0.x, x0.y, x0.z, x0.w, x1.x, x1.y, x1.z, x1.w,
                      x2.x, x2.y, x2.z, x2.w, x3.x, x3.y, x3.z, x3.w};
      float a0 = 0.f, a1 = 0.f;
      #pragma unroll
      for (int n = 0; n < 16; ++n) {
        a0 = fmaf(wA[n], xv[n], a0);
        a1 = fmaf(wB[n], xv[n], a1);
      }
      const size_t base = ((size_t)(b0 + bb) * I_ + i) * OD_ + od0;
      uhat[base]       = (uint16_t)f2bf1(a0);
      uhat[base + 256] = (uint16_t)f2bf1(a1);
      accA[bb] += a0;                 // fp32 pre-rounding accumulation
      accB[bb] += a1;
    }
  }
  #pragma unroll
  for (int bb = 0; bb < 4; ++bb) {
    const size_t pb = ((size_t)(b0 + bb) * NCH0 + chunk) * OD_ + od0;
    part0[pb]       = (uint16_t)f2bf1(accA[bb]);
    part0[pb + 256] = (uint16_t)f2bf1(accB[bb]);
  }
}

// ---------- squash: reduce NCH bf16 chunk-partials, scale, (+bias), squash over d ----------
template <int NCH>
__global__ __launch_bounds__(256) void k_squash(const uint16_t* __restrict__ part,
                                                const float* __restrict__ bias,
                                                float* __restrict__ vout,
                                                float scale, int addBias) {
  const int lane = threadIdx.x & 63;
  const int row = blockIdx.x * 4 + (threadIdx.x >> 6);  // b=row>>6, o=row&63
  const int b = row >> 6, o = row & 63;
  const int d = lane & 31;
  const uint16_t* p = part + (size_t)b * (NCH * OD_) + (size_t)o * 32 + d;
  float s = 0.f;
  const int c0 = (lane >> 5) * (NCH / 2);   // half-waves split the chunks
  #pragma unroll
  for (int c = 0; c < NCH / 2; ++c)
    s += __uint_as_float(((uint32_t)p[(size_t)(c0 + c) * OD_]) << 16);
  s += __shfl_xor(s, 32);
  s *= scale;
  if (addBias) s += bias[o * 32 + d];
  float dot = s * s;
  #pragma unroll
  for (int off = 1; off <= 16; off <<= 1) dot += __shfl_xor(dot, off);
  float sc = dot / (1.f + dot) / sqrtf(dot + 1e-8f);
  if (lane < 32) vout[(size_t)row * 32 + d] = s * sc;
}

// ---------- routing pass (iters 1 and 2), lane = o, minimal registers ----------
// (frozen — unchanged from the 297-µs known-good version)
__global__ __launch_bounds__(256) void k_route(const uint4* __restrict__ uhat,
                                               const float* __restrict__ vprev,
                                               float* __restrict__ bij,
                                               uint4* __restrict__ part,
                                               int secondIter) {
  const int b = blockIdx.x >> 5, chunk = blockIdx.x & 31;
  const int t = threadIdx.x;
  const int w = t >> 6, lane = t & 63;   // lane = o
  __shared__ float red[4][64][32];       // 32 KB, swizzled [w][o][(d+o)&31]
  uint32_t vp[16];
  {
    const float4* vpt = (const float4*)(vprev + ((size_t)b * 64 + lane) * 32);
    #pragma unroll
    for (int q = 0; q < 8; ++q) {
      float4 f = vpt[q];
      vp[2 * q]     = pack2(f.x, f.y);
      vp[2 * q + 1] = pack2(f.z, f.w);
    }
  }
  float s_acc[32];
  #pragma unroll
  for (int d = 0; d < 32; ++d) s_acc[d] = 0.f;
  const int i0 = chunk * 32 + w * 8;
  const uint4* ub = uhat + ((size_t)b * I_ + i0) * 256 + (size_t)lane * 4;
  for (int r = 0; r < 8; ++r) {
    const uint4* uc = ub + (size_t)r * 256;
    uint4 c0 = uc[0], c1 = uc[1], c2 = uc[2], c3 = uc[3];
    float a = 0.f;
    {
      float u8[8];
      unpack8(c0, u8);
      #pragma unroll
      for (int p = 0; p < 4; ++p) {
        uint32_t vv = vp[p];
        a = fmaf(u8[2 * p], bflo(vv), a);
        a = fmaf(u8[2 * p + 1], bfhi(vv), a);
      }
      unpack8(c1, u8);
      #pragma unroll
      for (int p = 0; p < 4; ++p) {
        uint32_t vv = vp[4 + p];
        a = fmaf(u8[2 * p], bflo(vv), a);
        a = fmaf(u8[2 * p + 1], bfhi(vv), a);
      }
      unpack8(c2, u8);
      #pragma unroll
      for (int p = 0; p < 4; ++p) {
        uint32_t vv = vp[8 + p];
        a = fmaf(u8[2 * p], bflo(vv), a);
        a = fmaf(u8[2 * p + 1], bfhi(vv), a);
      }
      unpack8(c3, u8);
      #pragma unroll
      for (int p = 0; p < 4; ++p) {
        uint32_t vv = vp[12 + p];
        a = fmaf(u8[2 * p], bflo(vv), a);
        a = fmaf(u8[2 * p + 1], bfhi(vv), a);
      }
    }
    const int i = i0 + r;
    const size_t bidx = ((size_t)b * I_ + i) * 64 + lane;
    float bn = a;
    if (secondIter) bn += bij[bidx];
    else            bij[bidx] = bn;
    float m = bn;
    #pragma unroll
    for (int off = 1; off <= 32; off <<= 1) m = fmaxf(m, __shfl_xor(m, off));
    float e = __expf(bn - m);
    float sm = e;
    #pragma unroll
    for (int off = 1; off <= 32; off <<= 1) sm += __shfl_xor(sm, off);
    const float c = e / sm;
    {
      float u8[8];
      unpack8(c0, u8);
      #pragma unroll
      for (int j = 0; j < 8; ++j) s_acc[j] = fmaf(c, u8[j], s_acc[j]);
      unpack8(c1, u8);
      #pragma unroll
      for (int j = 0; j < 8; ++j) s_acc[8 + j] = fmaf(c, u8[j], s_acc[8 + j]);
      unpack8(c2, u8);
      #pragma unroll
      for (int j = 0; j < 8; ++j) s_acc[16 + j] = fmaf(c, u8[j], s_acc[16 + j]);
      unpack8(c3, u8);
      #pragma unroll
      for (int j = 0; j < 8; ++j) s_acc[24 + j] = fmaf(c, u8[j], s_acc[24 + j]);
    }
  }
  #pragma unroll
  for (int d = 0; d < 32; ++d) red[w][lane][(d + lane) & 31] = s_acc[d];
  __syncthreads();
  {
    const int o = t >> 2, db = (t & 3) * 8;
    float sum[8];
    #pragma unroll
    for (int j = 0; j < 8; ++j) {
      const int sw = (db + j + o) & 31;
      sum[j] = red[0][o][sw] + red[1][o][sw] + red[2][o][sw] + red[3][o][sw];
    }
    part[(((size_t)b * 32 + chunk) * OD_ + (size_t)t * 8) >> 3] =
        make_uint4(pack2(sum[0], sum[1]), pack2(sum[2], sum[3]),
                   pack2(sum[4], sum[5]), pack2(sum[6], sum[7]));
  }
}

extern "C" void kernel_launch(void* const* d_in, const int* in_sizes, int n_in,
                              void* d_out, int out_size, void* d_ws, size_t ws_size,
                              hipStream_t stream) {
  const float* x    = (const float*)d_in[0];  // [32,1024,16]
  const float* W    = (const float*)d_in[1];  // [1,1024,64,32,16]
  const float* bias = (const float*)d_in[2];  // [1,1,64,32]
  float* out = (float*)d_out;                 // [32,64,32]

  char* ws = (char*)d_ws;
  // Workspace layout (140.25 MiB total — identical footprint to the proven 297-µs version):
  //   [0,128M)       uhat   bf16 u_hat[b][i][od]
  //   [128,136M)     part0  bf16 iter-0 partials [b][64][od]  (dead after squash0)
  //   [128,136M)     bij    fp32 b_ij[b,i,o]   (aliases part0; written in route1, AFTER part0 dead)
  //   [136,140M)     rpart  bf16 route partials [b][32][od]
  //   [140M,+256K)   vbuf   fp32 v[b,od]
  uint16_t* uhat1 = (uint16_t*)ws;
  uint4*    uhat4 = (uint4*)ws;
  uint16_t* part0 = (uint16_t*)(ws + 134217728ull);
  float*    bij   = (float*)   (ws + 134217728ull);
  uint4*    rpart = (uint4*)   (ws + 134217728ull + 8388608ull);
  uint16_t* rpart16 = (uint16_t*)rpart;
  float*    vbuf  = (float*)   (ws + 134217728ull + 8388608ull + 4194304ull);

  // fused einsum + iter-0 uniform sum (c = 1/64 applied in squash scale)
  k_einsum_sum<<<dim3(2048), dim3(256), 0, stream>>>(x, W, uhat1, part0);
  k_squash<NCH0><<<dim3(512), dim3(256), 0, stream>>>(part0, bias, vbuf, 1.f / 64.f, 0);
  // iter 1
  k_route<<<dim3(1024), dim3(256), 0, stream>>>(uhat4, vbuf, bij, rpart, 0);
  k_squash<32><<<dim3(512), dim3(256), 0, stream>>>(rpart16, bias, vbuf, 1.f, 0);
  // iter 2 (last): + bias, output
  k_route<<<dim3(1024), dim3(256), 0, stream>>>(uhat4, vbuf, bij, rpart, 1);
  k_squash<32><<<dim3(512), dim3(256), 0, stream>>>(rpart16, bias, out, 1.f, 1);
}

// Round 9
// 301.680 us; speedup vs baseline: 1.2656x; 1.2656x over previous
//
#include <hip/hip_runtime.h>
#include <hip/hip_bf16.h>
#include <stdint.h>

// Problem constants (FC_Caps): B=32, I=1024, O=64, D_out=32, D_in=16
#define B_  32
#define I_  1024
#define O_  64
#define D_  32
#define N_  16
#define OD_ 2048   // O_*D_

// ---------- bf16 helpers (bit-exact RNE pack, shift unpack) ----------
__device__ __forceinline__ uint32_t f2bf1(float f) {
  uint32_t u = __float_as_uint(f);
  return (u + 0x7fffu + ((u >> 16) & 1u)) >> 16;
}
__device__ __forceinline__ uint32_t pack2(float a, float b) {
  return f2bf1(a) | (f2bf1(b) << 16);
}
__device__ __forceinline__ float bflo(uint32_t v) { return __uint_as_float(v << 16); }
__device__ __forceinline__ float bfhi(uint32_t v) { return __uint_as_float(v & 0xffff0000u); }
__device__ __forceinline__ void unpack8(uint4 r, float* u) {
  u[0] = bflo(r.x); u[1] = bfhi(r.x);
  u[2] = bflo(r.y); u[3] = bfhi(r.y);
  u[4] = bflo(r.z); u[5] = bfhi(r.z);
  u[6] = bflo(r.w); u[7] = bfhi(r.w);
}

// ---------- K1: u_hat[b][i][od] = sum_n W[i,od,n] * x[b,i,n]  (bf16 out) ----------
// REVERTED to the proven 85-us structure (one i per block, W loaded ONCE per
// kernel, tight LDS-broadcast loop over 32 b). Session post-mortems R5-R7:
// every chunked-K1 fusion variant (134-230 us) lost more to load latency/ILP
// than the 21-us k_sum0 traffic saving gained. Fusion abandoned on evidence.
__global__ __launch_bounds__(256) void k_einsum(const float* __restrict__ x,
                                                const float* __restrict__ W,
                                                uint16_t* __restrict__ uhat) {
  const int i = blockIdx.x >> 2;
  const int q = blockIdx.x & 3;
  const int t = threadIdx.x;
  const int od0 = q * 512 + t;          // row A; row B = od0 + 256
  __shared__ float xs[B_ * N_];
  for (int e = t; e < B_ * N_; e += 256) {
    int bb = e >> 4, n = e & 15;
    xs[e] = x[(size_t)bb * (I_ * N_) + (size_t)i * N_ + n];
  }
  float wA[16], wB[16];
  {
    const float4* Wa = (const float4*)(W + (size_t)i * (OD_ * N_) + (size_t)od0 * N_);
    const float4* Wb = (const float4*)(W + (size_t)i * (OD_ * N_) + (size_t)(od0 + 256) * N_);
    #pragma unroll
    for (int qq = 0; qq < 4; ++qq) {
      float4 fa = Wa[qq];
      wA[qq * 4 + 0] = fa.x; wA[qq * 4 + 1] = fa.y;
      wA[qq * 4 + 2] = fa.z; wA[qq * 4 + 3] = fa.w;
      float4 fb = Wb[qq];
      wB[qq * 4 + 0] = fb.x; wB[qq * 4 + 1] = fb.y;
      wB[qq * 4 + 2] = fb.z; wB[qq * 4 + 3] = fb.w;
    }
  }
  __syncthreads();
  #pragma unroll 2
  for (int bb = 0; bb < B_; ++bb) {
    float4 x0 = ((const float4*)(xs + bb * 16))[0];
    float4 x1 = ((const float4*)(xs + bb * 16))[1];
    float4 x2 = ((const float4*)(xs + bb * 16))[2];
    float4 x3 = ((const float4*)(xs + bb * 16))[3];
    float xv[16] = {x0.x, x0.y, x0.z, x0.w, x1.x, x1.y, x1.z, x1.w,
                    x2.x, x2.y, x2.z, x2.w, x3.x, x3.y, x3.z, x3.w};
    float a0 = 0.f, a1 = 0.f;
    #pragma unroll
    for (int n = 0; n < 16; ++n) {
      a0 = fmaf(wA[n], xv[n], a0);
      a1 = fmaf(wB[n], xv[n], a1);
    }
    const size_t base = ((size_t)bb * I_ + i) * OD_ + od0;
    uhat[base]       = (uint16_t)f2bf1(a0);
    uhat[base + 256] = (uint16_t)f2bf1(a1);
  }
}

// ---------- K2: iter-0 weighted sum (c exactly uniform). chunk=32 i, bf16 partials ----------
// (restored from the 297-us baseline)
__global__ __launch_bounds__(256) void k_sum0(const uint4* __restrict__ uhat,
                                              uint4* __restrict__ part) {
  const int b = blockIdx.x >> 5, chunk = blockIdx.x & 31;
  const int t = threadIdx.x;
  float acc[8] = {0.f, 0.f, 0.f, 0.f, 0.f, 0.f, 0.f, 0.f};
  const size_t ubase = (((size_t)b * I_ + (size_t)chunk * 32) * OD_ + (size_t)t * 8) >> 3;
  #pragma unroll 8
  for (int ii = 0; ii < 32; ++ii) {
    uint4 r = uhat[ubase + (size_t)ii * (OD_ / 8)];
    float u[8]; unpack8(r, u);
    #pragma unroll
    for (int j = 0; j < 8; ++j) acc[j] += u[j];
  }
  part[(((size_t)b * 32 + chunk) * OD_ + (size_t)t * 8) >> 3] =
      make_uint4(pack2(acc[0], acc[1]), pack2(acc[2], acc[3]),
                 pack2(acc[4], acc[5]), pack2(acc[6], acc[7]));
}

// ---------- squash: reduce 32 bf16 chunk-partials, scale, (+bias), squash over d ----------
__global__ __launch_bounds__(256) void k_squash(const uint16_t* __restrict__ part,
                                                const float* __restrict__ bias,
                                                float* __restrict__ vout,
                                                float scale, int addBias) {
  const int lane = threadIdx.x & 63;
  const int row = blockIdx.x * 4 + (threadIdx.x >> 6);  // b=row>>6, o=row&63
  const int b = row >> 6, o = row & 63;
  const int d = lane & 31;
  const uint16_t* p = part + (size_t)b * (32 * OD_) + (size_t)o * 32 + d;
  float s = 0.f;
  const int c0 = (lane >> 5) * 16;   // half-waves split the 32 chunks
  for (int c = c0; c < c0 + 16; ++c)
    s += __uint_as_float(((uint32_t)p[(size_t)c * OD_]) << 16);
  s += __shfl_xor(s, 32);
  s *= scale;
  if (addBias) s += bias[o * 32 + d];
  float dot = s * s;
  #pragma unroll
  for (int off = 1; off <= 16; off <<= 1) dot += __shfl_xor(dot, off);
  float sc = dot / (1.f + dot) / sqrtf(dot + 1e-8f);
  if (lane < 32) vout[(size_t)row * 32 + d] = s * sc;
}

// ---------- routing pass (iters 1 and 2), lane = o ----------
// SINGLE CHANGE this round: register double-buffer prefetch of the next
// r-iteration's 4 uint4 u_hat loads, issued BEFORE the current iteration's
// FMA/softmax block. Theory: route was latency-bound (measured ~85 us vs
// ~22 us VALU + ~22 us mem per CU at 16 waves/CU) — the serial
// load->vmcnt->compute chain left HBM latency exposed. Prefetch overlaps
// it with ~400 cyc of compute. +16 VGPR (~98 live), no spill, occupancy
// unchanged (grid-limited at 4 blocks/CU).
__global__ __launch_bounds__(256) void k_route(const uint4* __restrict__ uhat,
                                               const float* __restrict__ vprev,
                                               float* __restrict__ bij,
                                               uint4* __restrict__ part,
                                               int secondIter) {
  const int b = blockIdx.x >> 5, chunk = blockIdx.x & 31;
  const int t = threadIdx.x;
  const int w = t >> 6, lane = t & 63;   // lane = o
  __shared__ float red[4][64][32];       // 32 KB, swizzled [w][o][(d+o)&31]
  uint32_t vp[16];
  {
    const float4* vpt = (const float4*)(vprev + ((size_t)b * 64 + lane) * 32);
    #pragma unroll
    for (int q = 0; q < 8; ++q) {
      float4 f = vpt[q];
      vp[2 * q]     = pack2(f.x, f.y);
      vp[2 * q + 1] = pack2(f.z, f.w);
    }
  }
  float s_acc[32];
  #pragma unroll
  for (int d = 0; d < 32; ++d) s_acc[d] = 0.f;
  const int i0 = chunk * 32 + w * 8;
  const uint4* ub = uhat + ((size_t)b * I_ + i0) * 256 + (size_t)lane * 4;
  // prime r=0
  uint4 c0 = ub[0], c1 = ub[1], c2 = ub[2], c3 = ub[3];
  for (int r = 0; r < 8; ++r) {
    uint4 n0, n1, n2, n3;
    if (r < 7) {                         // uniform branch; loads issue early,
      const uint4* un = ub + (size_t)(r + 1) * 256;  // overlap compute below
      n0 = un[0]; n1 = un[1]; n2 = un[2]; n3 = un[3];
    }
    float a = 0.f;
    {
      float u8[8];
      unpack8(c0, u8);
      #pragma unroll
      for (int p = 0; p < 4; ++p) {
        uint32_t vv = vp[p];
        a = fmaf(u8[2 * p], bflo(vv), a);
        a = fmaf(u8[2 * p + 1], bfhi(vv), a);
      }
      unpack8(c1, u8);
      #pragma unroll
      for (int p = 0; p < 4; ++p) {
        uint32_t vv = vp[4 + p];
        a = fmaf(u8[2 * p], bflo(vv), a);
        a = fmaf(u8[2 * p + 1], bfhi(vv), a);
      }
      unpack8(c2, u8);
      #pragma unroll
      for (int p = 0; p < 4; ++p) {
        uint32_t vv = vp[8 + p];
        a = fmaf(u8[2 * p], bflo(vv), a);
        a = fmaf(u8[2 * p + 1], bfhi(vv), a);
      }
      unpack8(c3, u8);
      #pragma unroll
      for (int p = 0; p < 4; ++p) {
        uint32_t vv = vp[12 + p];
        a = fmaf(u8[2 * p], bflo(vv), a);
        a = fmaf(u8[2 * p + 1], bfhi(vv), a);
      }
    }
    const int i = i0 + r;
    const size_t bidx = ((size_t)b * I_ + i) * 64 + lane;
    float bn = a;
    if (secondIter) bn += bij[bidx];
    else            bij[bidx] = bn;
    // wave softmax over the 64 o's
    float m = bn;
    #pragma unroll
    for (int off = 1; off <= 32; off <<= 1) m = fmaxf(m, __shfl_xor(m, off));
    float e = __expf(bn - m);
    float sm = e;
    #pragma unroll
    for (int off = 1; off <= 32; off <<= 1) sm += __shfl_xor(sm, off);
    const float c = e / sm;
    {
      float u8[8];
      unpack8(c0, u8);
      #pragma unroll
      for (int j = 0; j < 8; ++j) s_acc[j] = fmaf(c, u8[j], s_acc[j]);
      unpack8(c1, u8);
      #pragma unroll
      for (int j = 0; j < 8; ++j) s_acc[8 + j] = fmaf(c, u8[j], s_acc[8 + j]);
      unpack8(c2, u8);
      #pragma unroll
      for (int j = 0; j < 8; ++j) s_acc[16 + j] = fmaf(c, u8[j], s_acc[16 + j]);
      unpack8(c3, u8);
      #pragma unroll
      for (int j = 0; j < 8; ++j) s_acc[24 + j] = fmaf(c, u8[j], s_acc[24 + j]);
    }
    if (r < 7) { c0 = n0; c1 = n1; c2 = n2; c3 = n3; }
  }
  // combine the 4 waves' per-lane [o][d] partials (swizzle kills bank conflicts)
  #pragma unroll
  for (int d = 0; d < 32; ++d) red[w][lane][(d + lane) & 31] = s_acc[d];
  __syncthreads();
  {
    const int o = t >> 2, db = (t & 3) * 8;  // thread owns od = o*32 + db..db+7
    float sum[8];
    #pragma unroll
    for (int j = 0; j < 8; ++j) {
      const int sw = (db + j + o) & 31;
      sum[j] = red[0][o][sw] + red[1][o][sw] + red[2][o][sw] + red[3][o][sw];
    }
    part[(((size_t)b * 32 + chunk) * OD_ + (size_t)t * 8) >> 3] =
        make_uint4(pack2(sum[0], sum[1]), pack2(sum[2], sum[3]),
                   pack2(sum[4], sum[5]), pack2(sum[6], sum[7]));
  }
}

extern "C" void kernel_launch(void* const* d_in, const int* in_sizes, int n_in,
                              void* d_out, int out_size, void* d_ws, size_t ws_size,
                              hipStream_t stream) {
  const float* x    = (const float*)d_in[0];  // [32,1024,16]
  const float* W    = (const float*)d_in[1];  // [1,1024,64,32,16]
  const float* bias = (const float*)d_in[2];  // [1,1,64,32]
  float* out = (float*)d_out;                 // [32,64,32]

  char* ws = (char*)d_ws;
  // Workspace layout (140.25 MiB — the proven baseline layout):
  //   [0,128M)      uhat  bf16 u_hat[b][i][od]
  //   [128,136M)    bij   fp32 b_ij[b,i,o]
  //   [136,140M)    part  bf16 partials [b,32,od]
  //   [140M,+256K)  vbuf  fp32 v[b,od]
  uint16_t* uhat1 = (uint16_t*)ws;
  uint4*    uhat4 = (uint4*)ws;
  float* bij  = (float*)(ws + 134217728ull);
  uint4* part = (uint4*)(ws + 134217728ull + 8388608ull);
  uint16_t* part16 = (uint16_t*)part;
  float* vbuf = (float*)(ws + 134217728ull + 8388608ull + 4194304ull);

  k_einsum<<<dim3(I_ * 4), dim3(256), 0, stream>>>(x, W, uhat1);
  // iter 0: uniform c = 1/64
  k_sum0  <<<dim3(1024), dim3(256), 0, stream>>>(uhat4, part);
  k_squash<<<dim3(512),  dim3(256), 0, stream>>>(part16, bias, vbuf, 1.f / 64.f, 0);
  // iter 1
  k_route <<<dim3(1024), dim3(256), 0, stream>>>(uhat4, vbuf, bij, part, 0);
  k_squash<<<dim3(512),  dim3(256), 0, stream>>>(part16, bias, vbuf, 1.f, 0);
  // iter 2 (last): + bias, output
  k_route <<<dim3(1024), dim3(256), 0, stream>>>(uhat4, vbuf, bij, part, 1);
  k_squash<<<dim3(512),  dim3(256), 0, stream>>>(part16, bias, out, 1.f, 1);
}

// Round 10
// 298.682 us; speedup vs baseline: 1.2783x; 1.0100x over previous
//
#include <hip/hip_runtime.h>
#include <hip/hip_bf16.h>
#include <stdint.h>

// Problem constants (FC_Caps): B=32, I=1024, O=64, D_out=32, D_in=16
#define B_  32
#define I_  1024
#define O_  64
#define D_  32
#define N_  16
#define OD_ 2048   // O_*D_

// ---------- bf16 helpers (bit-exact RNE pack, shift unpack) ----------
__device__ __forceinline__ uint32_t f2bf1(float f) {
  uint32_t u = __float_as_uint(f);
  return (u + 0x7fffu + ((u >> 16) & 1u)) >> 16;
}
__device__ __forceinline__ uint32_t pack2(float a, float b) {
  return f2bf1(a) | (f2bf1(b) << 16);
}
__device__ __forceinline__ float bflo(uint32_t v) { return __uint_as_float(v << 16); }
__device__ __forceinline__ float bfhi(uint32_t v) { return __uint_as_float(v & 0xffff0000u); }
__device__ __forceinline__ void unpack8(uint4 r, float* u) {
  u[0] = bflo(r.x); u[1] = bfhi(r.x);
  u[2] = bflo(r.y); u[3] = bfhi(r.y);
  u[4] = bflo(r.z); u[5] = bfhi(r.z);
  u[6] = bflo(r.w); u[7] = bfhi(r.w);
}

// ---------- K1: u_hat[b][i][od] = sum_n W[i,od,n] * x[b,i,n]  (bf16 out) ----------
// R10 change (single variable vs the 85-us proven K1): thread owns the
// ADJACENT od pair (2t, 2t+1) instead of (t, t+256). The two bf16 results
// pack into ONE uint32 store: 64 -> 32 store insts/thread, each a full
// 256 B/wave segment (was 128 B). W rows for the pair are 128 B contiguous
// (one L1-friendly stream). Per-od FMA order unchanged -> u_hat bit-exact.
// Theory: einsum was issue-bound (85 us, VALUBusy 35%, HBM 30%, 74 mem
// insts/thread of which 64 are half-width stores).
__global__ __launch_bounds__(256) void k_einsum(const float* __restrict__ x,
                                                const float* __restrict__ W,
                                                uint16_t* __restrict__ uhat) {
  const int i = blockIdx.x >> 2;
  const int q = blockIdx.x & 3;
  const int t = threadIdx.x;
  const int od0 = q * 512 + t * 2;      // this thread owns od0 and od0+1
  __shared__ float xs[B_ * N_];
  for (int e = t; e < B_ * N_; e += 256) {
    int bb = e >> 4, n = e & 15;
    xs[e] = x[(size_t)bb * (I_ * N_) + (size_t)i * N_ + n];
  }
  float wA[16], wB[16];
  {
    // rows od0 (16 floats) and od0+1 (16 floats) are contiguous: 8 float4
    const float4* Wp = (const float4*)(W + (size_t)i * (OD_ * N_) + (size_t)od0 * N_);
    #pragma unroll
    for (int qq = 0; qq < 4; ++qq) {
      float4 fa = Wp[qq];
      wA[qq * 4 + 0] = fa.x; wA[qq * 4 + 1] = fa.y;
      wA[qq * 4 + 2] = fa.z; wA[qq * 4 + 3] = fa.w;
      float4 fb = Wp[4 + qq];
      wB[qq * 4 + 0] = fb.x; wB[qq * 4 + 1] = fb.y;
      wB[qq * 4 + 2] = fb.z; wB[qq * 4 + 3] = fb.w;
    }
  }
  __syncthreads();
  uint32_t* u32 = (uint32_t*)uhat;
  #pragma unroll 2
  for (int bb = 0; bb < B_; ++bb) {
    float4 x0 = ((const float4*)(xs + bb * 16))[0];
    float4 x1 = ((const float4*)(xs + bb * 16))[1];
    float4 x2 = ((const float4*)(xs + bb * 16))[2];
    float4 x3 = ((const float4*)(xs + bb * 16))[3];
    float xv[16] = {x0.x, x0.y, x0.z, x0.w, x1.x, x1.y, x1.z, x1.w,
                    x2.x, x2.y, x2.z, x2.w, x3.x, x3.y, x3.z, x3.w};
    float a0 = 0.f, a1 = 0.f;
    #pragma unroll
    for (int n = 0; n < 16; ++n) {
      a0 = fmaf(wA[n], xv[n], a0);
      a1 = fmaf(wB[n], xv[n], a1);
    }
    u32[(((size_t)bb * I_ + i) * OD_ + od0) >> 1] = pack2(a0, a1);
  }
}

// ---------- K2: iter-0 weighted sum (c exactly uniform). chunk=32 i, bf16 partials ----------
// (frozen — 297-us baseline form)
__global__ __launch_bounds__(256) void k_sum0(const uint4* __restrict__ uhat,
                                              uint4* __restrict__ part) {
  const int b = blockIdx.x >> 5, chunk = blockIdx.x & 31;
  const int t = threadIdx.x;
  float acc[8] = {0.f, 0.f, 0.f, 0.f, 0.f, 0.f, 0.f, 0.f};
  const size_t ubase = (((size_t)b * I_ + (size_t)chunk * 32) * OD_ + (size_t)t * 8) >> 3;
  #pragma unroll 8
  for (int ii = 0; ii < 32; ++ii) {
    uint4 r = uhat[ubase + (size_t)ii * (OD_ / 8)];
    float u[8]; unpack8(r, u);
    #pragma unroll
    for (int j = 0; j < 8; ++j) acc[j] += u[j];
  }
  part[(((size_t)b * 32 + chunk) * OD_ + (size_t)t * 8) >> 3] =
      make_uint4(pack2(acc[0], acc[1]), pack2(acc[2], acc[3]),
                 pack2(acc[4], acc[5]), pack2(acc[6], acc[7]));
}

// ---------- squash: reduce 32 bf16 chunk-partials, scale, (+bias), squash over d ----------
// (frozen — 297-us baseline form)
__global__ __launch_bounds__(256) void k_squash(const uint16_t* __restrict__ part,
                                                const float* __restrict__ bias,
                                                float* __restrict__ vout,
                                                float scale, int addBias) {
  const int lane = threadIdx.x & 63;
  const int row = blockIdx.x * 4 + (threadIdx.x >> 6);  // b=row>>6, o=row&63
  const int b = row >> 6, o = row & 63;
  const int d = lane & 31;
  const uint16_t* p = part + (size_t)b * (32 * OD_) + (size_t)o * 32 + d;
  float s = 0.f;
  const int c0 = (lane >> 5) * 16;   // half-waves split the 32 chunks
  for (int c = c0; c < c0 + 16; ++c)
    s += __uint_as_float(((uint32_t)p[(size_t)c * OD_]) << 16);
  s += __shfl_xor(s, 32);
  s *= scale;
  if (addBias) s += bias[o * 32 + d];
  float dot = s * s;
  #pragma unroll
  for (int off = 1; off <= 16; off <<= 1) dot += __shfl_xor(dot, off);
  float sc = dot / (1.f + dot) / sqrtf(dot + 1e-8f);
  if (lane < 32) vout[(size_t)row * 32 + d] = s * sc;
}

// ---------- routing pass (iters 1 and 2), lane = o ----------
// REVERTED to the exact 297-us baseline: R9's register prefetch was neutral
// (compiler already unrolls the constant r-loop and hoists loads); removing
// it drops ~16 VGPR and restores the known reference structure.
__global__ __launch_bounds__(256) void k_route(const uint4* __restrict__ uhat,
                                               const float* __restrict__ vprev,
                                               float* __restrict__ bij,
                                               uint4* __restrict__ part,
                                               int secondIter) {
  const int b = blockIdx.x >> 5, chunk = blockIdx.x & 31;
  const int t = threadIdx.x;
  const int w = t >> 6, lane = t & 63;   // lane = o
  __shared__ float red[4][64][32];       // 32 KB, swizzled [w][o][(d+o)&31]
  uint32_t vp[16];
  {
    const float4* vpt = (const float4*)(vprev + ((size_t)b * 64 + lane) * 32);
    #pragma unroll
    for (int q = 0; q < 8; ++q) {
      float4 f = vpt[q];
      vp[2 * q]     = pack2(f.x, f.y);
      vp[2 * q + 1] = pack2(f.z, f.w);
    }
  }
  float s_acc[32];
  #pragma unroll
  for (int d = 0; d < 32; ++d) s_acc[d] = 0.f;
  const int i0 = chunk * 32 + w * 8;
  const uint4* ub = uhat + ((size_t)b * I_ + i0) * 256 + (size_t)lane * 4;
  for (int r = 0; r < 8; ++r) {
    const uint4* uc = ub + (size_t)r * 256;
    uint4 c0 = uc[0], c1 = uc[1], c2 = uc[2], c3 = uc[3];
    float a = 0.f;
    {
      float u8[8];
      unpack8(c0, u8);
      #pragma unroll
      for (int p = 0; p < 4; ++p) {
        uint32_t vv = vp[p];
        a = fmaf(u8[2 * p], bflo(vv), a);
        a = fmaf(u8[2 * p + 1], bfhi(vv), a);
      }
      unpack8(c1, u8);
      #pragma unroll
      for (int p = 0; p < 4; ++p) {
        uint32_t vv = vp[4 + p];
        a = fmaf(u8[2 * p], bflo(vv), a);
        a = fmaf(u8[2 * p + 1], bfhi(vv), a);
      }
      unpack8(c2, u8);
      #pragma unroll
      for (int p = 0; p < 4; ++p) {
        uint32_t vv = vp[8 + p];
        a = fmaf(u8[2 * p], bflo(vv), a);
        a = fmaf(u8[2 * p + 1], bfhi(vv), a);
      }
      unpack8(c3, u8);
      #pragma unroll
      for (int p = 0; p < 4; ++p) {
        uint32_t vv = vp[12 + p];
        a = fmaf(u8[2 * p], bflo(vv), a);
        a = fmaf(u8[2 * p + 1], bfhi(vv), a);
      }
    }
    const int i = i0 + r;
    const size_t bidx = ((size_t)b * I_ + i) * 64 + lane;
    float bn = a;
    if (secondIter) bn += bij[bidx];
    else            bij[bidx] = bn;
    // wave softmax over the 64 o's
    float m = bn;
    #pragma unroll
    for (int off = 1; off <= 32; off <<= 1) m = fmaxf(m, __shfl_xor(m, off));
    float e = __expf(bn - m);
    float sm = e;
    #pragma unroll
    for (int off = 1; off <= 32; off <<= 1) sm += __shfl_xor(sm, off);
    const float c = e / sm;
    {
      float u8[8];
      unpack8(c0, u8);
      #pragma unroll
      for (int j = 0; j < 8; ++j) s_acc[j] = fmaf(c, u8[j], s_acc[j]);
      unpack8(c1, u8);
      #pragma unroll
      for (int j = 0; j < 8; ++j) s_acc[8 + j] = fmaf(c, u8[j], s_acc[8 + j]);
      unpack8(c2, u8);
      #pragma unroll
      for (int j = 0; j < 8; ++j) s_acc[16 + j] = fmaf(c, u8[j], s_acc[16 + j]);
      unpack8(c3, u8);
      #pragma unroll
      for (int j = 0; j < 8; ++j) s_acc[24 + j] = fmaf(c, u8[j], s_acc[24 + j]);
    }
  }
  // combine the 4 waves' per-lane [o][d] partials (swizzle kills bank conflicts)
  #pragma unroll
  for (int d = 0; d < 32; ++d) red[w][lane][(d + lane) & 31] = s_acc[d];
  __syncthreads();
  {
    const int o = t >> 2, db = (t & 3) * 8;  // thread owns od = o*32 + db..db+7
    float sum[8];
    #pragma unroll
    for (int j = 0; j < 8; ++j) {
      const int sw = (db + j + o) & 31;
      sum[j] = red[0][o][sw] + red[1][o][sw] + red[2][o][sw] + red[3][o][sw];
    }
    part[(((size_t)b * 32 + chunk) * OD_ + (size_t)t * 8) >> 3] =
        make_uint4(pack2(sum[0], sum[1]), pack2(sum[2], sum[3]),
                   pack2(sum[4], sum[5]), pack2(sum[6], sum[7]));
  }
}

extern "C" void kernel_launch(void* const* d_in, const int* in_sizes, int n_in,
                              void* d_out, int out_size, void* d_ws, size_t ws_size,
                              hipStream_t stream) {
  const float* x    = (const float*)d_in[0];  // [32,1024,16]
  const float* W    = (const float*)d_in[1];  // [1,1024,64,32,16]
  const float* bias = (const float*)d_in[2];  // [1,1,64,32]
  float* out = (float*)d_out;                 // [32,64,32]

  char* ws = (char*)d_ws;
  // Workspace layout (140.25 MiB — the proven baseline layout):
  //   [0,128M)      uhat  bf16 u_hat[b][i][od]
  //   [128,136M)    bij   fp32 b_ij[b,i,o]
  //   [136,140M)    part  bf16 partials [b,32,od]
  //   [140M,+256K)  vbuf  fp32 v[b,od]
  uint16_t* uhat1 = (uint16_t*)ws;
  uint4*    uhat4 = (uint4*)ws;
  float* bij  = (float*)(ws + 134217728ull);
  uint4* part = (uint4*)(ws + 134217728ull + 8388608ull);
  uint16_t* part16 = (uint16_t*)part;
  float* vbuf = (float*)(ws + 134217728ull + 8388608ull + 4194304ull);

  k_einsum<<<dim3(I_ * 4), dim3(256), 0, stream>>>(x, W, uhat1);
  // iter 0: uniform c = 1/64
  k_sum0  <<<dim3(1024), dim3(256), 0, stream>>>(uhat4, part);
  k_squash<<<dim3(512),  dim3(256), 0, stream>>>(part16, bias, vbuf, 1.f / 64.f, 0);
  // iter 1
  k_route <<<dim3(1024), dim3(256), 0, stream>>>(uhat4, vbuf, bij, part, 0);
  k_squash<<<dim3(512),  dim3(256), 0, stream>>>(part16, bias, vbuf, 1.f, 0);
  // iter 2 (last): + bias, output
  k_route <<<dim3(1024), dim3(256), 0, stream>>>(uhat4, vbuf, bij, part, 1);
  k_squash<<<dim3(512),  dim3(256), 0, stream>>>(part16, bias, out, 1.f, 1);
}